// Round 2
// baseline (1290.839 us; speedup 1.0000x reference)
//
#include <hip/hip_runtime.h>
#include <hip/hip_bf16.h>

// JetBlock forward: B=2, T=2048, HID=2048, H=16, DK=DV=128, W=4
//
// Precision strategy: all GEMMs use fp16 MFMA (mfma_f32_16x16x32_f16, same
// 2.5 PF rate as bf16 on gfx950 but 8x lower rounding). fp32 accumulate;
// recurrence fully fp32.
//
// Round 6: recurrence double-buffered (T14 async-stage). R5 counters:
// recurrence 529us = 42% of total, VALUBusy 46%, Occ 22%, HBM 5.6% --
// latency-bound serial chain PLUS ~10K cy/chunk synchronous staging stall
// (cold global loads drained at a barrier every 32 steps). Now: chunk c+1's
// q/k/v/decay/beta are loaded into REGISTERS before chunk c's serial loop
// (latency hides under ~10K cy of compute), the L2-norm pass is fused into
// the staging-write (register values reduced via red32 -- kills one barrier
// and an LDS re-read phase), and LDS q/k/v/prm are double-buffered.
// Barriers: 4/chunk -> 2/chunk.

typedef _Float16 v8h __attribute__((ext_vector_type(8)));
typedef _Float16 v4h __attribute__((ext_vector_type(4)));
typedef _Float16 v2h __attribute__((ext_vector_type(2)));
typedef float    v4f __attribute__((ext_vector_type(4)));

__device__ __forceinline__ void gload16(const void* g, void* l) {
  __builtin_amdgcn_global_load_lds(
      (const __attribute__((address_space(1))) unsigned int*)g,
      (__attribute__((address_space(3))) unsigned int*)l, 16, 0, 0);
}

// DPP-based partial-wave reduction (VALU pipe, not DS).
template<int CTRL>
__device__ __forceinline__ float dpp_add(float x) {
  int v = __builtin_amdgcn_update_dpp(0, __float_as_int(x), CTRL, 0xF, 0xF, true);
  return x + __int_as_float(v);
}
// Sum over each aligned 32-lane group, result broadcast to all 32 lanes.
__device__ __forceinline__ float red32(float x) {
  x = dpp_add<0xB1>(x);    // quad_perm [1,0,3,2] : xor 1
  x = dpp_add<0x4E>(x);    // quad_perm [2,3,0,1] : xor 2
  x = dpp_add<0x124>(x);   // row_ror:4
  x = dpp_add<0x128>(x);   // row_ror:8
  return x + __shfl_xor(x, 16);
}

// ---------------------------------------------------------------- transpose
// src [R][C] fp32 -> dst [C][R] fp16
__global__ __launch_bounds__(256)
void transpose_cast(const float* __restrict__ src, _Float16* __restrict__ dst,
                    int R, int C)
{
  __shared__ float tile[32][33];
  int c0 = blockIdx.x * 32, r0 = blockIdx.y * 32;
  int tx = threadIdx.x & 31, ty = threadIdx.x >> 5;  // ty 0..7
  #pragma unroll
  for (int i = 0; i < 32; i += 8)
    tile[ty + i][tx] = src[(size_t)(r0 + ty + i) * C + c0 + tx];
  __syncthreads();
  #pragma unroll
  for (int i = 0; i < 32; i += 8)
    dst[(size_t)(c0 + ty + i) * R + r0 + tx] = (_Float16)tile[tx][ty + i];
}

// ---------------------------------------------------------------- cast
__global__ __launch_bounds__(256)
void cast_f32_f16(const float* __restrict__ src, _Float16* __restrict__ dst, int n4)
{
  int i = blockIdx.x * 256 + threadIdx.x;
  if (i >= n4) return;
  float4 v = ((const float4*)src)[i];
  v4h h = {(_Float16)v.x, (_Float16)v.y, (_Float16)v.z, (_Float16)v.w};
  *(v4h*)&dst[4 * (size_t)i] = h;
}

// ---------------------------------------------------------------- GEMM 256x256 8-phase
// C[M][N] = A[M][K] * Bt[N][K]^T, fp16 in, fp32 accumulate.
// MODE 0: fp32 store. 1: silu -> f16. 2: +bias -> f16. 3: plain f16.
// (structure unchanged from Round 5 -- see header comment there)
template<int MODE>
__global__ __launch_bounds__(512, 2)
void gemm256(const _Float16* __restrict__ A, const _Float16* __restrict__ Bt,
             void* __restrict__ Cout, const float* __restrict__ bias,
             int M, int N, int K)
{
  __shared__ _Float16 lds[65536];   // 128 KiB
  const int tid  = threadIdx.x;
  const int lane = tid & 63;
  const int wid  = tid >> 6;
  const int wm   = wid >> 2;        // 0..1
  const int wn   = wid & 3;         // 0..3
  const int l16  = lane & 15;
  const int q8   = (lane >> 4) * 8;
  const int swzx = (l16 & 7) << 3;  // row&7 == l16&7 for all frag rows

  // XCD-aware bijective swizzle (gridDim.x % 8 == 0 at all call sites)
  const int nbx = N >> 8;
  const int cpx = gridDim.x >> 3;
  const int swz = (blockIdx.x & 7) * cpx + (blockIdx.x >> 3);
  const int bm0 = (swz / nbx) << 8;
  const int bn0 = (swz % nbx) << 8;

  const _Float16* Abase = A  + (size_t)bm0 * K;
  const _Float16* Bbase = Bt + (size_t)bn0 * K;

  const int r0 = tid >> 3;                              // 0..63
  const int cs = ((tid & 7) * 8) ^ ((r0 & 7) << 3);     // f16 units

#define SLOTA(par, half) (lds + ((par) * 2 + (half)) * 8192)
#define SLOTB(par, half) (lds + 32768 + ((par) * 2 + (half)) * 8192)
#define STAGE(basep, kt, slot) do {                                        \
    _Float16* sst_ = (slot);                                               \
    gload16((basep) + (size_t)r0 * K + (kt) + cs, sst_ + tid * 8);         \
    gload16((basep) + (size_t)(r0 + 64) * K + (kt) + cs,                   \
            sst_ + 4096 + tid * 8);                                        \
  } while (0)
#define LOADA(par, mh) do {                                                \
    const _Float16* sld_ = SLOTA(par, mh);                                 \
    _Pragma("unroll")                                                      \
    for (int ks = 0; ks < 2; ks++)                                         \
      _Pragma("unroll")                                                    \
      for (int mi = 0; mi < 4; mi++)                                       \
        af[ks][mi] = *(const v8h*)&sld_[(wm * 64 + mi * 16 + l16) * 64 +   \
                                        ((ks * 32 + q8) ^ swzx)];          \
  } while (0)
#define LOADB(par, nh) do {                                                \
    const _Float16* sld_ = SLOTB(par, nh);                                 \
    _Pragma("unroll")                                                      \
    for (int ks = 0; ks < 2; ks++)                                         \
      _Pragma("unroll")                                                    \
      for (int ni = 0; ni < 2; ni++)                                       \
        bf[ks][ni] = *(const v8h*)&sld_[(wn * 32 + ni * 16 + l16) * 64 +   \
                                        ((ks * 32 + q8) ^ swzx)];          \
  } while (0)
#define MMAC(mh, nh) do {                                                  \
    __builtin_amdgcn_s_setprio(1);                                         \
    _Pragma("unroll")                                                      \
    for (int ks = 0; ks < 2; ks++)                                         \
      _Pragma("unroll")                                                    \
      for (int mi = 0; mi < 4; mi++)                                       \
        _Pragma("unroll")                                                  \
        for (int ni = 0; ni < 2; ni++)                                     \
          acc[mh][mi][nh][ni] = __builtin_amdgcn_mfma_f32_16x16x32_f16(    \
              af[ks][mi], bf[ks][ni], acc[mh][mi][nh][ni], 0, 0, 0);       \
    __builtin_amdgcn_s_setprio(0);                                         \
  } while (0)

  v4f acc[2][4][2][2];
  #pragma unroll
  for (int mh = 0; mh < 2; mh++)
    #pragma unroll
    for (int mi = 0; mi < 4; mi++)
      #pragma unroll
      for (int nh = 0; nh < 2; nh++)
        #pragma unroll
        for (int ni = 0; ni < 2; ni++)
          acc[mh][mi][nh][ni] = v4f{0.f, 0.f, 0.f, 0.f};
  v8h af[2][4], bf[2][2];

  const int nt = K >> 6;   // >= 32 at all call sites

  // prologue: tile0 fully + t1.Aa + t1.Bb (steady-state pattern primed)
  STAGE(Abase,                   0,  SLOTA(0, 0));
  STAGE(Bbase,                   0,  SLOTB(0, 0));
  STAGE(Abase + (size_t)128 * K, 0,  SLOTA(0, 1));
  STAGE(Bbase + (size_t)128 * K, 0,  SLOTB(0, 1));
  STAGE(Abase,                   64, SLOTA(1, 0));
  STAGE(Bbase + (size_t)128 * K, 64, SLOTB(1, 1));
  asm volatile("s_waitcnt vmcnt(4)" ::: "memory");
  __builtin_amdgcn_s_barrier();

  for (int T = 0; T < nt; T++) {
    const int par = T & 1;
    const int kt1 = (T + 1) << 6;
    const int kt2 = (T + 2) << 6;
    // ph1 (0,0)
    LOADA(par, 0);
    LOADB(par, 0);
    if (T + 1 < nt) STAGE(Abase + (size_t)128 * K, kt1, SLOTA(par ^ 1, 1));
    __builtin_amdgcn_s_barrier();
    MMAC(0, 0);
    __builtin_amdgcn_s_barrier();
    // ph2 (0,1)
    LOADB(par, 1);
    if (T + 1 < nt) STAGE(Bbase, kt1, SLOTB(par ^ 1, 0));
    __builtin_amdgcn_s_barrier();
    MMAC(0, 1);
    __builtin_amdgcn_s_barrier();
    // ph3 (1,1)
    LOADA(par, 1);
    if (T + 2 < nt) STAGE(Abase, kt2, SLOTA(par, 0));
    __builtin_amdgcn_s_barrier();
    MMAC(1, 1);
    __builtin_amdgcn_s_barrier();
    // ph4 (1,0)
    LOADB(par, 0);
    if (T + 2 < nt) STAGE(Bbase + (size_t)128 * K, kt2, SLOTB(par, 1));
    __builtin_amdgcn_s_barrier();
    MMAC(1, 0);
    if (T + 2 < nt) { asm volatile("s_waitcnt vmcnt(4)" ::: "memory"); }
    else            { asm volatile("s_waitcnt vmcnt(0)" ::: "memory"); }
    __builtin_amdgcn_s_barrier();
  }

  const int q4 = (lane >> 4) * 4;
  #pragma unroll
  for (int mh = 0; mh < 2; mh++) {
    #pragma unroll
    for (int mi = 0; mi < 4; mi++) {
      #pragma unroll
      for (int nh = 0; nh < 2; nh++) {
        #pragma unroll
        for (int ni = 0; ni < 2; ni++) {
          const int gn = bn0 + nh * 128 + wn * 32 + ni * 16 + l16;
          #pragma unroll
          for (int r = 0; r < 4; r++) {
            const int gm = bm0 + mh * 128 + wm * 64 + mi * 16 + q4 + r;
            float val = acc[mh][mi][nh][ni][r];
            size_t offc = (size_t)gm * N + gn;
            if (MODE == 0) {
              ((float*)Cout)[offc] = val;
            } else if (MODE == 1) {
              float s = val / (1.0f + expf(-val));
              ((_Float16*)Cout)[offc] = (_Float16)s;
            } else if (MODE == 2) {
              float s = val + bias[gn];
              ((_Float16*)Cout)[offc] = (_Float16)s;
            } else {
              ((_Float16*)Cout)[offc] = (_Float16)val;
            }
          }
        }
      }
    }
  }
#undef SLOTA
#undef SLOTB
#undef STAGE
#undef LOADA
#undef LOADB
#undef MMAC
}

// ---------------------------------------------------------------- conv + silu (per 2048-row chunk == one batch)
__global__ __launch_bounds__(256)
void conv_silu(const _Float16* __restrict__ vg, const _Float16* __restrict__ kernc,
               float* __restrict__ vprime, int chunk)
{
  int idx = blockIdx.x * 256 + threadIdx.x;   // 2048*2048
  int btl = idx >> 11;                        // 0..2047 == t (chunk aligned to batch)
  int d   = idx & 2047;
  int btg = chunk * 2048 + btl;
  v4h kv = *(const v4h*)&kernc[(size_t)btl * 8192 + d * 4];
  float kw0 = (float)kv[0], kw1 = (float)kv[1], kw2 = (float)kv[2], kw3 = (float)kv[3];
  const _Float16* vcol = vg + d;
  float acc = kw3 * (float)vcol[(size_t)btg * 4096];
  if (btl >= 1) acc += kw2 * (float)vcol[(size_t)(btg - 1) * 4096];
  if (btl >= 2) acc += kw1 * (float)vcol[(size_t)(btg - 2) * 4096];
  if (btl >= 3) acc += kw0 * (float)vcol[(size_t)(btg - 3) * 4096];
  vprime[(size_t)btg * 2048 + d] = acc / (1.0f + expf(-acc));
}

// ---------------------------------------------------------------- beta / decay (fp32 x)
__global__ __launch_bounds__(256)
void beta_decay(const float* __restrict__ x, const float* __restrict__ Wb,
                const float* __restrict__ Wa, const float* __restrict__ dt_bias,
                const float* __restrict__ A_log,
                float* __restrict__ beta, float* __restrict__ decay)
{
  __shared__ float xs[2048];
  __shared__ float red[8][32];
  int row = blockIdx.x;
  int tid = threadIdx.x;
  for (int i = tid; i < 2048; i += 256) xs[i] = x[(size_t)row * 2048 + i];
  __syncthreads();
  int j = tid & 31, kg = tid >> 5;
  const float* W = (j < 16) ? Wb : Wa;
  int jj = j & 15;
  float acc = 0.f;
  int k0 = kg * 256;
  for (int k = k0; k < k0 + 256; k++) acc += xs[k] * W[(size_t)k * 16 + jj];
  red[kg][j] = acc;
  __syncthreads();
  if (tid < 32) {
    float s = 0.f;
    #pragma unroll
    for (int g2 = 0; g2 < 8; g2++) s += red[g2][tid];
    int hh = tid & 15;
    if (tid < 16) {
      beta[(size_t)row * 16 + hh] = 1.0f / (1.0f + expf(-s));
    } else {
      float tt = s + dt_bias[hh];
      float sp = (tt > 20.f) ? tt : log1pf(expf(tt));
      decay[(size_t)row * 16 + hh] = expf(-expf(A_log[hh]) * sp);
    }
  }
}

// ---------------------------------------------------------------- recurrence (Round 6)
// 512 blocks = (b, h, vq16): 8 DV columns per block. 256 thr: vc = tid>>5
// (column), kg = tid&31 (4-element k slice).
// Double-buffered: chunk c+1's q/k (v4h x4), v, decay/beta are global-loaded
// into REGISTERS before chunk c's ~10K-cycle serial loop (T14), then
// converted->LDS buf^1 + row-norms (red32 on register values, fused) after
// the serial loop. 2 barriers/chunk (was 4). LDS 69KB -> 2 blocks/CU.
#define RCH 32
__global__ __launch_bounds__(256)
void recurrence(const _Float16* __restrict__ gi, const float* __restrict__ vprime,
                const float* __restrict__ beta, const float* __restrict__ decay,
                float* __restrict__ o)
{
  __shared__ float qs[2][RCH][128];
  __shared__ float ks[2][RCH][128];
  __shared__ float vs[2][RCH][8];
  __shared__ float os[RCH][8];
  __shared__ float4 prm[2][RCH];  // {decay, beta, 1/||q||, 1/||k||}

  const int blk = blockIdx.x;     // 512
  const int vq = blk & 15;
  const int h  = (blk >> 4) & 15;
  const int b  = blk >> 8;
  const int vbase = vq * 8;
  const int tid = threadIdx.x;
  const int vc = tid >> 5;        // 0..7 (column)
  const int kg = tid & 31;        // 0..31 (k slice)
  const int col = kg * 4;         // staging column (fp32 units)
  const int vr_r = tid >> 3, vr_c = tid & 7;
  float S[4] = {0.f, 0.f, 0.f, 0.f};

  const _Float16* gq = gi + (size_t)b * 2048 * 4096 + h * 128;
  const _Float16* gk = gq + 2048;

  v4h qr[4], kr[4];
  float vr = 0.f, dec = 0.f, bet = 0.f;

  // issue chunk loads into registers (non-blocking; waitcnt lands at convert)
#define LOADC(t0) do {                                                      \
    _Pragma("unroll")                                                       \
    for (int j = 0; j < 4; j++) {                                           \
      int r_ = j * 8 + vc;                                                  \
      qr[j] = *(const v4h*)(gq + (size_t)((t0) + r_) * 4096 + col);         \
      kr[j] = *(const v4h*)(gk + (size_t)((t0) + r_) * 4096 + col);         \
    }                                                                       \
    vr = vprime[(size_t)(b * 2048 + (t0) + vr_r) * 2048 + h * 128 + vbase + vr_c]; \
    if (tid < RCH) {                                                        \
      size_t bt_ = (size_t)(b * 2048 + (t0) + tid);                         \
      dec = decay[bt_ * 16 + h];                                            \
      bet = beta[bt_ * 16 + h];                                             \
    }                                                                       \
  } while (0)

  // convert regs -> LDS buf, fused row L2-norms via red32 on register values
#define STOREC(buf) do {                                                    \
    _Pragma("unroll")                                                       \
    for (int j = 0; j < 4; j++) {                                           \
      int r_ = j * 8 + vc;                                                  \
      float4 qf = {(float)qr[j][0], (float)qr[j][1], (float)qr[j][2], (float)qr[j][3]}; \
      float4 kf = {(float)kr[j][0], (float)kr[j][1], (float)kr[j][2], (float)kr[j][3]}; \
      *(float4*)&qs[buf][r_][col] = qf;                                     \
      *(float4*)&ks[buf][r_][col] = kf;                                     \
      float sq = qf.x * qf.x + qf.y * qf.y + qf.z * qf.z + qf.w * qf.w;     \
      float sk = kf.x * kf.x + kf.y * kf.y + kf.z * kf.z + kf.w * kf.w;     \
      sq = red32(sq);                                                       \
      sk = red32(sk);                                                       \
      if (kg == 0) {                                                        \
        prm[buf][r_].z = 1.0f / fmaxf(sqrtf(sq), 1e-12f);                   \
        prm[buf][r_].w = 1.0f / fmaxf(sqrtf(sk), 1e-12f);                   \
      }                                                                     \
    }                                                                       \
    vs[buf][vr_r][vr_c] = vr;                                               \
    if (tid < RCH) { prm[buf][tid].x = dec; prm[buf][tid].y = bet; }        \
  } while (0)

  LOADC(0);
  STOREC(0);
  __syncthreads();

  for (int c = 0; c < 64; c++) {
    const int p = c & 1;
    if (c + 1 < 64) {
      LOADC((c + 1) * RCH);
      __builtin_amdgcn_sched_barrier(0);  // pin load issue before serial loop
    }
    const float (*qsb)[128] = qs[p];
    const float (*ksb)[128] = ks[p];
    v4f qc = *(const v4f*)&qsb[0][col];
    v4f kc = *(const v4f*)&ksb[0][col];
    #pragma unroll 4
    for (int r = 0; r < RCH; r++) {
      v4f qn, kn;
      if (r + 1 < RCH) {
        qn = *(const v4f*)&qsb[r + 1][col];
        kn = *(const v4f*)&ksb[r + 1][col];
      }
      float dq = qc[0] * S[0] + qc[1] * S[1] + qc[2] * S[2] + qc[3] * S[3];
      float dk = kc[0] * S[0] + kc[1] * S[1] + kc[2] * S[2] + kc[3] * S[3];
      dq = red32(dq);
      dk = red32(dk);
      float4 p4 = prm[p][r];
      float delta = vs[p][r][vc] - dk * p4.w;      // v_t - S^T k_hat (old S)
      float bd = p4.y * delta * p4.w;
      S[0] = p4.x * S[0] + bd * kc[0];
      S[1] = p4.x * S[1] + bd * kc[1];
      S[2] = p4.x * S[2] + bd * kc[2];
      S[3] = p4.x * S[3] + bd * kc[3];
      if (kg == 0) os[r][vc] = dq * p4.z;          // o_t = S_old^T q_hat
      qc = qn; kc = kn;
    }
    __syncthreads();   // os complete; prev buf fully consumed
    o[((size_t)(b * 2048 + c * RCH + vr_r) * 16 + h) * 128 + vbase + vr_c] =
        os[vr_r][vr_c];
    if (c + 1 < 64) STOREC(p ^ 1);
    __syncthreads();   // buf^1 + prm ready; os drained before next writes
  }
#undef LOADC
#undef STOREC
}

// ---------------------------------------------------------------- rmsnorm * silu(gate)
__global__ __launch_bounds__(256)
void rms_gate(const float* __restrict__ o, const _Float16* __restrict__ vg,
              const float* __restrict__ normw, _Float16* __restrict__ yh)
{
  int task = blockIdx.x * 4 + (threadIdx.x >> 6);  // bt*16+h, 0..65535
  int lane = threadIdx.x & 63;
  int bt = task >> 4, h = task & 15;
  float2 v = *(const float2*)(o + (size_t)task * 128 + lane * 2);
  float ss = v.x * v.x + v.y * v.y;
  #pragma unroll
  for (int m = 1; m < 64; m <<= 1) ss += __shfl_xor(ss, m);
  float r = rsqrtf(ss * (1.0f / 128.0f) + 1e-6f);
  v2h gt2 = *(const v2h*)(vg + (size_t)bt * 4096 + 2048 + h * 128 + lane * 2);
  float gx = (float)gt2[0], gy = (float)gt2[1];
  float2 nw = *(const float2*)(normw + lane * 2);
  float g0 = gx / (1.0f + expf(-gx));
  float g1 = gy / (1.0f + expf(-gy));
  v2h outp = {(_Float16)(v.x * r * nw.x * g0), (_Float16)(v.y * r * nw.y * g1)};
  *(v2h*)(yh + (size_t)bt * 2048 + h * 128 + lane * 2) = outp;
}

// ---------------------------------------------------------------- launch
extern "C" void kernel_launch(void* const* d_in, const int* in_sizes, int n_in,
                              void* d_out, int out_size, void* d_ws, size_t ws_size,
                              hipStream_t stream)
{
  (void)in_sizes; (void)n_in; (void)out_size;
  const float* x       = (const float*)d_in[0];
  const float* Wq      = (const float*)d_in[1];
  const float* Wk      = (const float*)d_in[2];
  const float* Wv      = (const float*)d_in[3];
  const float* Wb      = (const float*)d_in[4];
  const float* Wa      = (const float*)d_in[5];
  const float* dt_bias = (const float*)d_in[6];
  const float* A_log   = (const float*)d_in[7];
  const float* gen_w1  = (const float*)d_in[8];
  const float* gen_w2  = (const float*)d_in[9];
  const float* gen_b2  = (const float*)d_in[10];
  const float* normw   = (const float*)d_in[11];
  const float* Wg      = (const float*)d_in[12];
  const float* Wo      = (const float*)d_in[13];

  // ---- workspace pool (explicit aliasing; peak ~185 MB, known to fit) ----
  const size_t SZ_GI   = 4096ull * 4096 * 2;   // 33.5 MB  f16 q|k (pre-norm)
  const size_t SZ_VG   = 4096ull * 4096 * 2;   // 33.5 MB  f16 v|gate
  const size_t SZ_WT   = 8192ull * 2048 * 2;   // 33.5 MB  f16 transposed weights (reused)
  const size_t SZ_D    = 4096ull * 2048 * 2;   // 16.8 MB  xh -> hid -> yh
  const size_t SZ_KC   = 2048ull * 8192 * 2;   // 33.5 MB  kern chunk (reused)
  const size_t SZ_VP   = 4096ull * 2048 * 4;   // 33.5 MB  fp32 v'
  const size_t SZ_SM   = 4096ull * 16 * 4;     //  0.26 MB x2
  const size_t NEEDED = SZ_GI + SZ_VG + SZ_WT + SZ_D + SZ_KC + SZ_VP + 2 * SZ_SM;
  if (ws_size < NEEDED) return;

  char* w = (char*)d_ws;
  _Float16* gi     = (_Float16*)(w);
  _Float16* vg     = (_Float16*)(w + SZ_GI);
  _Float16* Wt     = (_Float16*)(w + SZ_GI + SZ_VG);
  char*     Dreg   =            (w + SZ_GI + SZ_VG + SZ_WT);
  _Float16* kernc  = (_Float16*)(w + SZ_GI + SZ_VG + SZ_WT + SZ_D);
  float*    vprime = (float*)   (w + SZ_GI + SZ_VG + SZ_WT + SZ_D + SZ_KC);
  float*    betab  = (float*)   (w + SZ_GI + SZ_VG + SZ_WT + SZ_D + SZ_KC + SZ_VP);
  float*    decayb = (float*)   (w + SZ_GI + SZ_VG + SZ_WT + SZ_D + SZ_KC + SZ_VP + SZ_SM);
  _Float16* xh  = (_Float16*)Dreg;  // until G1b
  _Float16* hid = (_Float16*)Dreg;  // G2 -> G3
  _Float16* yh  = (_Float16*)Dreg;  // rms_gate -> G4
  float* obuf = (float*)d_out;      // o lives in d_out until G4 overwrites

  dim3 blk(256);
  dim3 blk512(512);

  cast_f32_f16<<<8192, blk, 0, stream>>>(x, xh, 4096 * 2048 / 4);

  // G1a: q|k  (M=4096, N=4096, K=2048 -> 256 wgs)
  transpose_cast<<<dim3(64, 64), blk, 0, stream>>>(Wq, Wt, 2048, 2048);
  transpose_cast<<<dim3(64, 64), blk, 0, stream>>>(Wk, Wt + 2048 * 2048, 2048, 2048);
  gemm256<3><<<256, blk512, 0, stream>>>(xh, Wt, gi, nullptr, 4096, 4096, 2048);

  // G1b: v|gate
  transpose_cast<<<dim3(64, 64), blk, 0, stream>>>(Wv, Wt, 2048, 2048);
  transpose_cast<<<dim3(64, 64), blk, 0, stream>>>(Wg, Wt + 2048 * 2048, 2048, 2048);
  gemm256<3><<<256, blk512, 0, stream>>>(xh, Wt, vg, nullptr, 4096, 4096, 2048);

  // G2: hid = silu(gi @ gen_w1)  (M=4096, N=2048, K=4096 -> 128 wgs)
  transpose_cast<<<dim3(64, 128), blk, 0, stream>>>(gen_w1, Wt, 4096, 2048);
  gemm256<1><<<128, blk512, 0, stream>>>(gi, Wt, hid, nullptr, 4096, 2048, 4096);

  // G3 + conv, chunked per batch  (M=2048, N=8192, K=2048 -> 256 wgs)
  transpose_cast<<<dim3(256, 64), blk, 0, stream>>>(gen_w2, Wt, 2048, 8192);
  for (int chunk = 0; chunk < 2; chunk++) {
    gemm256<2><<<256, blk512, 0, stream>>>(hid + (size_t)chunk * 2048 * 2048, Wt,
                                           kernc, gen_b2, 2048, 8192, 2048);
    conv_silu<<<16384, blk, 0, stream>>>(vg, kernc, vprime, chunk);
  }

  beta_decay<<<4096, blk, 0, stream>>>(x, Wb, Wa, dt_bias, A_log, betab, decayb);
  recurrence<<<512, blk, 0, stream>>>(gi, vprime, betab, decayb, obuf);
  rms_gate<<<16384, blk, 0, stream>>>(obuf, vg, normw, yh);

  // G4: out = y @ Wo  (M=4096, N=2048, K=2048 -> 128 wgs)
  transpose_cast<<<dim3(64, 64), blk, 0, stream>>>(Wo, Wt, 2048, 2048);
  gemm256<0><<<128, blk512, 0, stream>>>(yh, Wt, (float*)d_out, nullptr, 4096, 2048, 2048);
}

// Round 3
// 1101.857 us; speedup vs baseline: 1.1715x; 1.1715x over previous
//
#include <hip/hip_runtime.h>
#include <hip/hip_bf16.h>

// JetBlock forward: B=2, T=2048, HID=2048, H=16, DK=DV=128, W=4
//
// Round 7: recurrence rewritten as CHUNKED delta-rule (UT transform, C=32).
// R6 evidence: per-timestep scan is VALU-work-bound (VALUBusy 59%, dur
// unchanged by staging overlap) -- the serial formulation is the floor.
// Chunked form: within a 32-step chunk, U = (I+A)^{-1}(beta*V - beta*Gm1*K S0),
// O = diag(Gm1) Q S0 + B U, S' = P31 S0 + Kp^T U. All dense parts are MFMA;
// only the 32-step triangular solve stays serial (1 bpermute + 8 FMA/step).
// State master kept fp32 in MFMA accumulators across all 64 chunks.

typedef _Float16 v8h __attribute__((ext_vector_type(8)));
typedef _Float16 v4h __attribute__((ext_vector_type(4)));
typedef _Float16 v2h __attribute__((ext_vector_type(2)));
typedef float    v4f __attribute__((ext_vector_type(4)));

__device__ __forceinline__ void gload16(const void* g, void* l) {
  __builtin_amdgcn_global_load_lds(
      (const __attribute__((address_space(1))) unsigned int*)g,
      (__attribute__((address_space(3))) unsigned int*)l, 16, 0, 0);
}

// ---------------------------------------------------------------- transpose
// src [R][C] fp32 -> dst [C][R] fp16
__global__ __launch_bounds__(256)
void transpose_cast(const float* __restrict__ src, _Float16* __restrict__ dst,
                    int R, int C)
{
  __shared__ float tile[32][33];
  int c0 = blockIdx.x * 32, r0 = blockIdx.y * 32;
  int tx = threadIdx.x & 31, ty = threadIdx.x >> 5;  // ty 0..7
  #pragma unroll
  for (int i = 0; i < 32; i += 8)
    tile[ty + i][tx] = src[(size_t)(r0 + ty + i) * C + c0 + tx];
  __syncthreads();
  #pragma unroll
  for (int i = 0; i < 32; i += 8)
    dst[(size_t)(c0 + ty + i) * R + r0 + tx] = (_Float16)tile[tx][ty + i];
}

// ---------------------------------------------------------------- cast
__global__ __launch_bounds__(256)
void cast_f32_f16(const float* __restrict__ src, _Float16* __restrict__ dst, int n4)
{
  int i = blockIdx.x * 256 + threadIdx.x;
  if (i >= n4) return;
  float4 v = ((const float4*)src)[i];
  v4h h = {(_Float16)v.x, (_Float16)v.y, (_Float16)v.z, (_Float16)v.w};
  *(v4h*)&dst[4 * (size_t)i] = h;
}

// ---------------------------------------------------------------- GEMM 256x256 8-phase
// C[M][N] = A[M][K] * Bt[N][K]^T, fp16 in, fp32 accumulate.
// MODE 0: fp32 store. 1: silu -> f16. 2: +bias -> f16. 3: plain f16.
// (structure unchanged from Round 5 -- see that round's derivation)
template<int MODE>
__global__ __launch_bounds__(512, 2)
void gemm256(const _Float16* __restrict__ A, const _Float16* __restrict__ Bt,
             void* __restrict__ Cout, const float* __restrict__ bias,
             int M, int N, int K)
{
  __shared__ _Float16 lds[65536];   // 128 KiB
  const int tid  = threadIdx.x;
  const int lane = tid & 63;
  const int wid  = tid >> 6;
  const int wm   = wid >> 2;        // 0..1
  const int wn   = wid & 3;         // 0..3
  const int l16  = lane & 15;
  const int q8   = (lane >> 4) * 8;
  const int swzx = (l16 & 7) << 3;  // row&7 == l16&7 for all frag rows

  // XCD-aware bijective swizzle (gridDim.x % 8 == 0 at all call sites)
  const int nbx = N >> 8;
  const int cpx = gridDim.x >> 3;
  const int swz = (blockIdx.x & 7) * cpx + (blockIdx.x >> 3);
  const int bm0 = (swz / nbx) << 8;
  const int bn0 = (swz % nbx) << 8;

  const _Float16* Abase = A  + (size_t)bm0 * K;
  const _Float16* Bbase = Bt + (size_t)bn0 * K;

  const int r0 = tid >> 3;                              // 0..63
  const int cs = ((tid & 7) * 8) ^ ((r0 & 7) << 3);     // f16 units

#define SLOTA(par, half) (lds + ((par) * 2 + (half)) * 8192)
#define SLOTB(par, half) (lds + 32768 + ((par) * 2 + (half)) * 8192)
#define STAGE(basep, kt, slot) do {                                        \
    _Float16* sst_ = (slot);                                               \
    gload16((basep) + (size_t)r0 * K + (kt) + cs, sst_ + tid * 8);         \
    gload16((basep) + (size_t)(r0 + 64) * K + (kt) + cs,                   \
            sst_ + 4096 + tid * 8);                                        \
  } while (0)
#define LOADA(par, mh) do {                                                \
    const _Float16* sld_ = SLOTA(par, mh);                                 \
    _Pragma("unroll")                                                      \
    for (int ks = 0; ks < 2; ks++)                                         \
      _Pragma("unroll")                                                    \
      for (int mi = 0; mi < 4; mi++)                                       \
        af[ks][mi] = *(const v8h*)&sld_[(wm * 64 + mi * 16 + l16) * 64 +   \
                                        ((ks * 32 + q8) ^ swzx)];          \
  } while (0)
#define LOADB(par, nh) do {                                                \
    const _Float16* sld_ = SLOTB(par, nh);                                 \
    _Pragma("unroll")                                                      \
    for (int ks = 0; ks < 2; ks++)                                         \
      _Pragma("unroll")                                                    \
      for (int ni = 0; ni < 2; ni++)                                       \
        bf[ks][ni] = *(const v8h*)&sld_[(wn * 32 + ni * 16 + l16) * 64 +   \
                                        ((ks * 32 + q8) ^ swzx)];          \
  } while (0)
#define MMAC(mh, nh) do {                                                  \
    __builtin_amdgcn_s_setprio(1);                                         \
    _Pragma("unroll")                                                      \
    for (int ks = 0; ks < 2; ks++)                                         \
      _Pragma("unroll")                                                    \
      for (int mi = 0; mi < 4; mi++)                                       \
        _Pragma("unroll")                                                  \
        for (int ni = 0; ni < 2; ni++)                                     \
          acc[mh][mi][nh][ni] = __builtin_amdgcn_mfma_f32_16x16x32_f16(    \
              af[ks][mi], bf[ks][ni], acc[mh][mi][nh][ni], 0, 0, 0);       \
    __builtin_amdgcn_s_setprio(0);                                         \
  } while (0)

  v4f acc[2][4][2][2];
  #pragma unroll
  for (int mh = 0; mh < 2; mh++)
    #pragma unroll
    for (int mi = 0; mi < 4; mi++)
      #pragma unroll
      for (int nh = 0; nh < 2; nh++)
        #pragma unroll
        for (int ni = 0; ni < 2; ni++)
          acc[mh][mi][nh][ni] = v4f{0.f, 0.f, 0.f, 0.f};
  v8h af[2][4], bf[2][2];

  const int nt = K >> 6;   // >= 32 at all call sites

  // prologue: tile0 fully + t1.Aa + t1.Bb (steady-state pattern primed)
  STAGE(Abase,                   0,  SLOTA(0, 0));
  STAGE(Bbase,                   0,  SLOTB(0, 0));
  STAGE(Abase + (size_t)128 * K, 0,  SLOTA(0, 1));
  STAGE(Bbase + (size_t)128 * K, 0,  SLOTB(0, 1));
  STAGE(Abase,                   64, SLOTA(1, 0));
  STAGE(Bbase + (size_t)128 * K, 64, SLOTB(1, 1));
  asm volatile("s_waitcnt vmcnt(4)" ::: "memory");
  __builtin_amdgcn_s_barrier();

  for (int T = 0; T < nt; T++) {
    const int par = T & 1;
    const int kt1 = (T + 1) << 6;
    const int kt2 = (T + 2) << 6;
    // ph1 (0,0)
    LOADA(par, 0);
    LOADB(par, 0);
    if (T + 1 < nt) STAGE(Abase + (size_t)128 * K, kt1, SLOTA(par ^ 1, 1));
    __builtin_amdgcn_s_barrier();
    MMAC(0, 0);
    __builtin_amdgcn_s_barrier();
    // ph2 (0,1)
    LOADB(par, 1);
    if (T + 1 < nt) STAGE(Bbase, kt1, SLOTB(par ^ 1, 0));
    __builtin_amdgcn_s_barrier();
    MMAC(0, 1);
    __builtin_amdgcn_s_barrier();
    // ph3 (1,1)
    LOADA(par, 1);
    if (T + 2 < nt) STAGE(Abase, kt2, SLOTA(par, 0));
    __builtin_amdgcn_s_barrier();
    MMAC(1, 1);
    __builtin_amdgcn_s_barrier();
    // ph4 (1,0)
    LOADB(par, 0);
    if (T + 2 < nt) STAGE(Bbase + (size_t)128 * K, kt2, SLOTB(par, 1));
    __builtin_amdgcn_s_barrier();
    MMAC(1, 0);
    if (T + 2 < nt) { asm volatile("s_waitcnt vmcnt(4)" ::: "memory"); }
    else            { asm volatile("s_waitcnt vmcnt(0)" ::: "memory"); }
    __builtin_amdgcn_s_barrier();
  }

  const int q4 = (lane >> 4) * 4;
  #pragma unroll
  for (int mh = 0; mh < 2; mh++) {
    #pragma unroll
    for (int mi = 0; mi < 4; mi++) {
      #pragma unroll
      for (int nh = 0; nh < 2; nh++) {
        #pragma unroll
        for (int ni = 0; ni < 2; ni++) {
          const int gn = bn0 + nh * 128 + wn * 32 + ni * 16 + l16;
          #pragma unroll
          for (int r = 0; r < 4; r++) {
            const int gm = bm0 + mh * 128 + wm * 64 + mi * 16 + q4 + r;
            float val = acc[mh][mi][nh][ni][r];
            size_t offc = (size_t)gm * N + gn;
            if (MODE == 0) {
              ((float*)Cout)[offc] = val;
            } else if (MODE == 1) {
              float s = val / (1.0f + expf(-val));
              ((_Float16*)Cout)[offc] = (_Float16)s;
            } else if (MODE == 2) {
              float s = val + bias[gn];
              ((_Float16*)Cout)[offc] = (_Float16)s;
            } else {
              ((_Float16*)Cout)[offc] = (_Float16)val;
            }
          }
        }
      }
    }
  }
#undef SLOTA
#undef SLOTB
#undef STAGE
#undef LOADA
#undef LOADB
#undef MMAC
}

// ---------------------------------------------------------------- conv + silu (per 2048-row chunk == one batch)
__global__ __launch_bounds__(256)
void conv_silu(const _Float16* __restrict__ vg, const _Float16* __restrict__ kernc,
               float* __restrict__ vprime, int chunk)
{
  int idx = blockIdx.x * 256 + threadIdx.x;   // 2048*2048
  int btl = idx >> 11;                        // 0..2047 == t (chunk aligned to batch)
  int d   = idx & 2047;
  int btg = chunk * 2048 + btl;
  v4h kv = *(const v4h*)&kernc[(size_t)btl * 8192 + d * 4];
  float kw0 = (float)kv[0], kw1 = (float)kv[1], kw2 = (float)kv[2], kw3 = (float)kv[3];
  const _Float16* vcol = vg + d;
  float acc = kw3 * (float)vcol[(size_t)btg * 4096];
  if (btl >= 1) acc += kw2 * (float)vcol[(size_t)(btg - 1) * 4096];
  if (btl >= 2) acc += kw1 * (float)vcol[(size_t)(btg - 2) * 4096];
  if (btl >= 3) acc += kw0 * (float)vcol[(size_t)(btg - 3) * 4096];
  vprime[(size_t)btg * 2048 + d] = acc / (1.0f + expf(-acc));
}

// ---------------------------------------------------------------- beta / glog (fp32 x)
// NOTE: now stores glog (log-space decay, <= 0), NOT exp(glog) -- the
// chunked recurrence needs log-space cumsums to avoid underflow.
__global__ __launch_bounds__(256)
void beta_decay(const float* __restrict__ x, const float* __restrict__ Wb,
                const float* __restrict__ Wa, const float* __restrict__ dt_bias,
                const float* __restrict__ A_log,
                float* __restrict__ beta, float* __restrict__ glog)
{
  __shared__ float xs[2048];
  __shared__ float red[8][32];
  int row = blockIdx.x;
  int tid = threadIdx.x;
  for (int i = tid; i < 2048; i += 256) xs[i] = x[(size_t)row * 2048 + i];
  __syncthreads();
  int j = tid & 31, kg = tid >> 5;
  const float* W = (j < 16) ? Wb : Wa;
  int jj = j & 15;
  float acc = 0.f;
  int k0 = kg * 256;
  for (int k = k0; k < k0 + 256; k++) acc += xs[k] * W[(size_t)k * 16 + jj];
  red[kg][j] = acc;
  __syncthreads();
  if (tid < 32) {
    float s = 0.f;
    #pragma unroll
    for (int g2 = 0; g2 < 8; g2++) s += red[g2][tid];
    int hh = tid & 15;
    if (tid < 16) {
      beta[(size_t)row * 16 + hh] = 1.0f / (1.0f + expf(-s));
    } else {
      float tt = s + dt_bias[hh];
      float sp = (tt > 20.f) ? tt : log1pf(expf(tt));
      glog[(size_t)row * 16 + hh] = -expf(A_log[hh]) * sp;
    }
  }
}

// ---------------------------------------------------------------- chunked recurrence (Round 7)
// 64 blocks = (b, h, dv-half). 256 thr = 4 waves. Chunk C=32.
// Per chunk: phase A = MFMAs {KK^T, QK^T, K*S0, Q*S0} + A/B matrix assembly;
// phase B = 32-step triangular solve of (I+A)U = beta*V - beta*Gm1*(K S0),
// per-wave over 16 dv cols (1 bpermute + 2 LDS broadcast + 8 FMA per step);
// phase C = MFMAs {O += B U, S = P31*S + Kp^T U} + o write + next-chunk
// staging (normalize q/k -> fp16 LDS + K^T copy + log-decay scan).
// State master: fp32 MFMA accumulators (8 v4f/lane), never leaves registers.
__global__ __launch_bounds__(256)
void recurrence_chunked(const _Float16* __restrict__ gi,
                        const float* __restrict__ vprime,
                        const float* __restrict__ betab,
                        const float* __restrict__ glogb,
                        float* __restrict__ o)
{
  // padded strides: 136/40 f16 (272/80 B) and 68/65 f32 keep all MFMA frag
  // reads <=2-way bank-aliased (free) and 16B-aligned.
  __shared__ _Float16 Q16[32][136];
  __shared__ _Float16 K16[32][136];
  __shared__ _Float16 KT16[2][128][40];   // K^T, double-buffered (read+write in C)
  __shared__ _Float16 St16[64][136];      // fp16 shadow of state (dv-major)
  __shared__ float V32[32][68];
  __shared__ float W0L[32][65];           // K*S0
  __shared__ float O0L[32][65];           // Q*S0
  __shared__ float At32[32][32];          // A transposed [j][i], upper zeroed
  __shared__ _Float16 B16[32][40];        // B matrix fp16 (row-major)
  __shared__ _Float16 Ut16[64][40];       // U^T fp16 (dv-major)
  __shared__ _Float16 Utp16[64][40];      // U^T scaled by P31/P_j
  __shared__ float lgA[2][32], lgm1A[2][32], gm1E[2][32], bGA[2][32],
                   psA[2][32], betA[2][32], p31A[2];

  const int tid  = threadIdx.x;
  const int wid  = tid >> 6;
  const int lane = tid & 63;
  const int l16  = lane & 15;
  const int q8   = (lane >> 4) * 8;
  const int q4   = (lane >> 4) * 4;
  const int rg   = lane >> 4;            // solve: row group (8 rows)
  const int wc   = wid * 16 + l16;       // solve: dv column (0..63)

  const int blk = blockIdx.x;            // 64
  const int dvh = blk & 1;
  const int h   = (blk >> 1) & 15;
  const int b   = blk >> 5;

  const _Float16* gq = gi + (size_t)b * 2048 * 4096 + h * 128;
  const _Float16* gk = gq + 2048;
  const float* vsrc = vprime + (size_t)b * 2048 * 2048 + h * 128 + dvh * 64;
  float* ob = o + ((size_t)b * 2048 * 16 + h) * 128 + dvh * 64;

  const int sr  = tid >> 3;              // staging row 0..31
  const int sc8 = tid & 7;
  const int c0  = sc8 * 16;              // q/k col base (16 f16 per thread)

  v4f sfr[8];                            // state frags: dv tile = wid, dk tiles 0..7
  #pragma unroll
  for (int tn = 0; tn < 8; tn++) sfr[tn] = v4f{0.f, 0.f, 0.f, 0.f};

  v8h pq0, pq1, pk0, pk1;
  float4 pv0, pv1;
  float pg = 0.f, pb = 0.f;

  auto stage_regs = [&](int t0) {
    pq0 = *(const v8h*)(gq + (size_t)(t0 + sr) * 4096 + c0);
    pq1 = *(const v8h*)(gq + (size_t)(t0 + sr) * 4096 + c0 + 8);
    pk0 = *(const v8h*)(gk + (size_t)(t0 + sr) * 4096 + c0);
    pk1 = *(const v8h*)(gk + (size_t)(t0 + sr) * 4096 + c0 + 8);
    pv0 = *(const float4*)(vsrc + (size_t)(t0 + sr) * 2048 + sc8 * 8);
    pv1 = *(const float4*)(vsrc + (size_t)(t0 + sr) * 2048 + sc8 * 8 + 4);
    if (tid < 32) {
      size_t bt_ = (size_t)(b * 2048 + t0 + tid) * 16 + h;
      pg = glogb[bt_];
      pb = betab[bt_];
    }
  };

  auto write_stage = [&](int pn) {
    float qf[16], kf[16];
    #pragma unroll
    for (int m = 0; m < 8; m++) {
      qf[m] = (float)pq0[m]; qf[m + 8] = (float)pq1[m];
      kf[m] = (float)pk0[m]; kf[m + 8] = (float)pk1[m];
    }
    float ssq = 0.f, ssk = 0.f;
    #pragma unroll
    for (int m = 0; m < 16; m++) { ssq += qf[m] * qf[m]; ssk += kf[m] * kf[m]; }
    ssq += __shfl_xor(ssq, 1); ssq += __shfl_xor(ssq, 2); ssq += __shfl_xor(ssq, 4);
    ssk += __shfl_xor(ssk, 1); ssk += __shfl_xor(ssk, 2); ssk += __shfl_xor(ssk, 4);
    float iq = 1.0f / fmaxf(sqrtf(ssq), 1e-12f);
    float ik = 1.0f / fmaxf(sqrtf(ssk), 1e-12f);
    v8h qo0, qo1, ko0, ko1;
    #pragma unroll
    for (int m = 0; m < 8; m++) {
      qo0[m] = (_Float16)(qf[m] * iq); qo1[m] = (_Float16)(qf[m + 8] * iq);
      ko0[m] = (_Float16)(kf[m] * ik); ko1[m] = (_Float16)(kf[m + 8] * ik);
    }
    *(v8h*)&Q16[sr][c0]     = qo0;
    *(v8h*)&Q16[sr][c0 + 8] = qo1;
    *(v8h*)&K16[sr][c0]     = ko0;
    *(v8h*)&K16[sr][c0 + 8] = ko1;
    #pragma unroll
    for (int m = 0; m < 8; m++) {
      KT16[pn][c0 + m][sr]     = ko0[m];
      KT16[pn][c0 + 8 + m][sr] = ko1[m];
    }
    *(float4*)&V32[sr][sc8 * 8]     = pv0;
    *(float4*)&V32[sr][sc8 * 8 + 4] = pv1;
    if (tid < 32) {
      // inclusive log-decay scan over the 32 chunk rows (lanes 0..31, wave 0)
      float s = pg;
      #pragma unroll
      for (int d = 1; d < 32; d <<= 1) {
        float t = __shfl_up(s, d, 64);
        if (lane >= d) s += t;
      }
      float lg31 = __shfl(s, 31, 64);
      float lgm1 = s - pg;               // log prod_{m<i} g_m
      lgA[pn][lane]   = s;
      lgm1A[pn][lane] = lgm1;
      float g1 = expf(lgm1);
      gm1E[pn][lane]  = g1;
      bGA[pn][lane]   = pb * g1;
      psA[pn][lane]   = expf(lg31 - s);  // P31/P_j <= 1
      betA[pn][lane]  = pb;
      if (lane == 0) p31A[pn] = expf(lg31);
    }
  };

  // ---- preloop: stage chunk 0, zero state shadow ----
  stage_regs(0);
  for (int i = tid; i < 64 * 136; i += 256) (&St16[0][0])[i] = (_Float16)0.f;
  write_stage(0);
  __syncthreads();

  const v4f zf = {0.f, 0.f, 0.f, 0.f};

  for (int c = 0; c < 64; c++) {
    const int par = c & 1;

    // ================= phase A: dense MFMAs + A/B assembly =================
    if (c < 63) { stage_regs((c + 1) * 32); __builtin_amdgcn_sched_barrier(0); }

    v4f kkf = zf, qkf = zf, w0f0 = zf, w0f1 = zf, o0f0 = zf, o0f1 = zf;
    {
      const int ai = (wid >> 1) * 16 + l16;  // KK/QK A rows (i)
      const int bj = (wid & 1) * 16 + l16;   // KK/QK B rows (j)
      #pragma unroll
      for (int ks = 0; ks < 4; ks++) {
        const int ko = ks * 32 + q8;
        v8h bs  = *(const v8h*)&St16[wid * 16 + l16][ko];  // S0 dv-slice
        v8h ak0 = *(const v8h*)&K16[l16][ko];
        v8h ak1 = *(const v8h*)&K16[16 + l16][ko];
        v8h aq0 = *(const v8h*)&Q16[l16][ko];
        v8h aq1 = *(const v8h*)&Q16[16 + l16][ko];
        w0f0 = __builtin_amdgcn_mfma_f32_16x16x32_f16(ak0, bs, w0f0, 0, 0, 0);
        w0f1 = __builtin_amdgcn_mfma_f32_16x16x32_f16(ak1, bs, w0f1, 0, 0, 0);
        o0f0 = __builtin_amdgcn_mfma_f32_16x16x32_f16(aq0, bs, o0f0, 0, 0, 0);
        o0f1 = __builtin_amdgcn_mfma_f32_16x16x32_f16(aq1, bs, o0f1, 0, 0, 0);
        v8h akk = *(const v8h*)&K16[ai][ko];
        v8h aqq = *(const v8h*)&Q16[ai][ko];
        v8h bkk = *(const v8h*)&K16[bj][ko];
        kkf = __builtin_amdgcn_mfma_f32_16x16x32_f16(akk, bkk, kkf, 0, 0, 0);
        qkf = __builtin_amdgcn_mfma_f32_16x16x32_f16(aqq, bkk, qkf, 0, 0, 0);
      }
    }
    {
      const int i0 = (wid >> 1) * 16, j = (wid & 1) * 16 + l16;
      #pragma unroll
      for (int fr = 0; fr < 4; fr++) {
        const int i = i0 + q4 + fr;
        float ex = expf(fminf(lgm1A[par][i] - lgA[par][j], 0.f));
        const bool lt = (j < i);
        At32[j][i] = lt ? betA[par][i] * ex * kkf[fr] : 0.f;
        B16[i][j]  = lt ? (_Float16)(ex * qkf[fr]) : (_Float16)0.f;
      }
      #pragma unroll
      for (int fr = 0; fr < 4; fr++) {
        W0L[q4 + fr][wid * 16 + l16]      = w0f0[fr];
        W0L[16 + q4 + fr][wid * 16 + l16] = w0f1[fr];
        O0L[q4 + fr][wid * 16 + l16]      = o0f0[fr];
        O0L[16 + q4 + fr][wid * 16 + l16] = o0f1[fr];
      }
    }
    __syncthreads();

    // ================= phase B: triangular solve (I+A)U = R =================
    float ru[8];
    #pragma unroll
    for (int jj = 0; jj < 8; jj++) {
      const int row = rg * 8 + jj;
      ru[jj] = betA[par][row] * V32[row][wc] - bGA[par][row] * W0L[row][wc];
    }
    #pragma unroll
    for (int j = 0; j < 32; j++) {
      float uj = __shfl(ru[j & 7], (j >> 3) * 16 + l16, 64);
      const v4f a0 = *(const v4f*)&At32[j][rg * 8];
      const v4f a1 = *(const v4f*)&At32[j][rg * 8 + 4];
      ru[0] -= a0[0] * uj; ru[1] -= a0[1] * uj;
      ru[2] -= a0[2] * uj; ru[3] -= a0[3] * uj;
      ru[4] -= a1[0] * uj; ru[5] -= a1[1] * uj;
      ru[6] -= a1[2] * uj; ru[7] -= a1[3] * uj;
    }
    {
      v8h uo, upo;
      #pragma unroll
      for (int jj = 0; jj < 8; jj++) {
        uo[jj]  = (_Float16)ru[jj];
        upo[jj] = (_Float16)(ru[jj] * psA[par][rg * 8 + jj]);
      }
      *(v8h*)&Ut16[wc][rg * 8]  = uo;
      *(v8h*)&Utp16[wc][rg * 8] = upo;
    }
    __syncthreads();

    // ================= phase C: O = Gm1*O0 + B U ; S = P31*S + Kp^T U =======
    {
      v8h bu = *(const v8h*)&Ut16[wid * 16 + l16][q8];
      #pragma unroll
      for (int t2i = 0; t2i < 2; t2i++) {
        v8h a = *(const v8h*)&B16[t2i * 16 + l16][q8];
        v4f d = __builtin_amdgcn_mfma_f32_16x16x32_f16(a, bu, zf, 0, 0, 0);
        #pragma unroll
        for (int fr = 0; fr < 4; fr++) {
          const int i = t2i * 16 + q4 + fr;
          const int cc = wid * 16 + l16;
          ob[(size_t)(c * 32 + i) * 2048 + cc] =
              gm1E[par][i] * O0L[i][cc] + d[fr];
        }
      }
      const float p31 = p31A[par];
      v8h ua = *(const v8h*)&Utp16[wid * 16 + l16][q8];
      #pragma unroll
      for (int tn = 0; tn < 8; tn++) {
        v8h bk = *(const v8h*)&KT16[par][tn * 16 + l16][q8];
        v4f sc = {sfr[tn][0] * p31, sfr[tn][1] * p31,
                  sfr[tn][2] * p31, sfr[tn][3] * p31};
        sfr[tn] = __builtin_amdgcn_mfma_f32_16x16x32_f16(ua, bk, sc, 0, 0, 0);
        #pragma unroll
        for (int fr = 0; fr < 4; fr++)
          St16[wid * 16 + q4 + fr][tn * 16 + l16] = (_Float16)sfr[tn][fr];
      }
    }
    if (c < 63) write_stage((c + 1) & 1);
    __syncthreads();
  }
}

// ---------------------------------------------------------------- rmsnorm * silu(gate)
__global__ __launch_bounds__(256)
void rms_gate(const float* __restrict__ o, const _Float16* __restrict__ vg,
              const float* __restrict__ normw, _Float16* __restrict__ yh)
{
  int task = blockIdx.x * 4 + (threadIdx.x >> 6);  // bt*16+h, 0..65535
  int lane = threadIdx.x & 63;
  int bt = task >> 4, h = task & 15;
  float2 v = *(const float2*)(o + (size_t)task * 128 + lane * 2);
  float ss = v.x * v.x + v.y * v.y;
  #pragma unroll
  for (int m = 1; m < 64; m <<= 1) ss += __shfl_xor(ss, m);
  float r = rsqrtf(ss * (1.0f / 128.0f) + 1e-6f);
  v2h gt2 = *(const v2h*)(vg + (size_t)bt * 4096 + 2048 + h * 128 + lane * 2);
  float gx = (float)gt2[0], gy = (float)gt2[1];
  float2 nw = *(const float2*)(normw + lane * 2);
  float g0 = gx / (1.0f + expf(-gx));
  float g1 = gy / (1.0f + expf(-gy));
  v2h outp = {(_Float16)(v.x * r * nw.x * g0), (_Float16)(v.y * r * nw.y * g1)};
  *(v2h*)(yh + (size_t)bt * 2048 + h * 128 + lane * 2) = outp;
}

// ---------------------------------------------------------------- launch
extern "C" void kernel_launch(void* const* d_in, const int* in_sizes, int n_in,
                              void* d_out, int out_size, void* d_ws, size_t ws_size,
                              hipStream_t stream)
{
  (void)in_sizes; (void)n_in; (void)out_size;
  const float* x       = (const float*)d_in[0];
  const float* Wq      = (const float*)d_in[1];
  const float* Wk      = (const float*)d_in[2];
  const float* Wv      = (const float*)d_in[3];
  const float* Wb      = (const float*)d_in[4];
  const float* Wa      = (const float*)d_in[5];
  const float* dt_bias = (const float*)d_in[6];
  const float* A_log   = (const float*)d_in[7];
  const float* gen_w1  = (const float*)d_in[8];
  const float* gen_w2  = (const float*)d_in[9];
  const float* gen_b2  = (const float*)d_in[10];
  const float* normw   = (const float*)d_in[11];
  const float* Wg      = (const float*)d_in[12];
  const float* Wo      = (const float*)d_in[13];

  // ---- workspace pool (explicit aliasing; peak ~185 MB, known to fit) ----
  const size_t SZ_GI   = 4096ull * 4096 * 2;   // 33.5 MB  f16 q|k (pre-norm)
  const size_t SZ_VG   = 4096ull * 4096 * 2;   // 33.5 MB  f16 v|gate
  const size_t SZ_WT   = 8192ull * 2048 * 2;   // 33.5 MB  f16 transposed weights (reused)
  const size_t SZ_D    = 4096ull * 2048 * 2;   // 16.8 MB  xh -> hid -> yh
  const size_t SZ_KC   = 2048ull * 8192 * 2;   // 33.5 MB  kern chunk (reused)
  const size_t SZ_VP   = 4096ull * 2048 * 4;   // 33.5 MB  fp32 v'
  const size_t SZ_SM   = 4096ull * 16 * 4;     //  0.26 MB x2
  const size_t NEEDED = SZ_GI + SZ_VG + SZ_WT + SZ_D + SZ_KC + SZ_VP + 2 * SZ_SM;
  if (ws_size < NEEDED) return;

  char* w = (char*)d_ws;
  _Float16* gi     = (_Float16*)(w);
  _Float16* vg     = (_Float16*)(w + SZ_GI);
  _Float16* Wt     = (_Float16*)(w + SZ_GI + SZ_VG);
  char*     Dreg   =            (w + SZ_GI + SZ_VG + SZ_WT);
  _Float16* kernc  = (_Float16*)(w + SZ_GI + SZ_VG + SZ_WT + SZ_D);
  float*    vprime = (float*)   (w + SZ_GI + SZ_VG + SZ_WT + SZ_D + SZ_KC);
  float*    betab  = (float*)   (w + SZ_GI + SZ_VG + SZ_WT + SZ_D + SZ_KC + SZ_VP);
  float*    glogb  = (float*)   (w + SZ_GI + SZ_VG + SZ_WT + SZ_D + SZ_KC + SZ_VP + SZ_SM);
  _Float16* xh  = (_Float16*)Dreg;  // until G1b
  _Float16* hid = (_Float16*)Dreg;  // G2 -> G3
  _Float16* yh  = (_Float16*)Dreg;  // rms_gate -> G4
  float* obuf = (float*)d_out;      // o lives in d_out until G4 overwrites

  dim3 blk(256);
  dim3 blk512(512);

  cast_f32_f16<<<8192, blk, 0, stream>>>(x, xh, 4096 * 2048 / 4);

  // G1a: q|k  (M=4096, N=4096, K=2048 -> 256 wgs)
  transpose_cast<<<dim3(64, 64), blk, 0, stream>>>(Wq, Wt, 2048, 2048);
  transpose_cast<<<dim3(64, 64), blk, 0, stream>>>(Wk, Wt + 2048 * 2048, 2048, 2048);
  gemm256<3><<<256, blk512, 0, stream>>>(xh, Wt, gi, nullptr, 4096, 4096, 2048);

  // G1b: v|gate
  transpose_cast<<<dim3(64, 64), blk, 0, stream>>>(Wv, Wt, 2048, 2048);
  transpose_cast<<<dim3(64, 64), blk, 0, stream>>>(Wg, Wt + 2048 * 2048, 2048, 2048);
  gemm256<3><<<256, blk512, 0, stream>>>(xh, Wt, vg, nullptr, 4096, 4096, 2048);

  // G2: hid = silu(gi @ gen_w1)  (M=4096, N=2048, K=4096 -> 128 wgs)
  transpose_cast<<<dim3(64, 128), blk, 0, stream>>>(gen_w1, Wt, 4096, 2048);
  gemm256<1><<<128, blk512, 0, stream>>>(gi, Wt, hid, nullptr, 4096, 2048, 4096);

  // G3 + conv, chunked per batch  (M=2048, N=8192, K=2048 -> 256 wgs)
  transpose_cast<<<dim3(256, 64), blk, 0, stream>>>(gen_w2, Wt, 2048, 8192);
  for (int chunk = 0; chunk < 2; chunk++) {
    gemm256<2><<<256, blk512, 0, stream>>>(hid + (size_t)chunk * 2048 * 2048, Wt,
                                           kernc, gen_b2, 2048, 8192, 2048);
    conv_silu<<<16384, blk, 0, stream>>>(vg, kernc, vprime, chunk);
  }

  beta_decay<<<4096, blk, 0, stream>>>(x, Wb, Wa, dt_bias, A_log, betab, glogb);
  recurrence_chunked<<<64, blk, 0, stream>>>(gi, vprime, betab, glogb, obuf);
  rms_gate<<<16384, blk, 0, stream>>>(obuf, vg, normw, yh);

  // G4: out = y @ Wo  (M=4096, N=2048, K=2048 -> 128 wgs)
  transpose_cast<<<dim3(64, 64), blk, 0, stream>>>(Wo, Wt, 2048, 2048);
  gemm256<0><<<128, blk512, 0, stream>>>(yh, Wt, (float*)d_out, nullptr, 4096, 2048, 2048);
}

// Round 4
// 968.943 us; speedup vs baseline: 1.3322x; 1.1372x over previous
//
#include <hip/hip_runtime.h>
#include <hip/hip_bf16.h>

// JetBlock forward: B=2, T=2048, HID=2048, H=16, DK=DV=128, W=4
//
// Round 8: recurrence parallelized across 2 sequence segments via affine
// superposition (the delta-rule state map is linear: S_t = (g I - b kk^T)S +
// b k v^T). One 192-block dispatch runs {seg0 real, seg1 real (S0=0),
// seg1 basis (S0=I, V=0)} concurrently; a small MFMA kernel then applies
// o[seg1] += o_basis @ S_end(seg0)^T. Serial depth 64->32 chunks, active
// CUs 64->192. Plus KT16 write swizzle (16-way -> 4-way bank conflicts,
// was 21% of recurrence cycles).

typedef _Float16 v8h __attribute__((ext_vector_type(8)));
typedef _Float16 v4h __attribute__((ext_vector_type(4)));
typedef _Float16 v2h __attribute__((ext_vector_type(2)));
typedef float    v4f __attribute__((ext_vector_type(4)));

__device__ __forceinline__ void gload16(const void* g, void* l) {
  __builtin_amdgcn_global_load_lds(
      (const __attribute__((address_space(1))) unsigned int*)g,
      (__attribute__((address_space(3))) unsigned int*)l, 16, 0, 0);
}

// ---------------------------------------------------------------- transpose
// src [R][C] fp32 -> dst [C][R] fp16
__global__ __launch_bounds__(256)
void transpose_cast(const float* __restrict__ src, _Float16* __restrict__ dst,
                    int R, int C)
{
  __shared__ float tile[32][33];
  int c0 = blockIdx.x * 32, r0 = blockIdx.y * 32;
  int tx = threadIdx.x & 31, ty = threadIdx.x >> 5;  // ty 0..7
  #pragma unroll
  for (int i = 0; i < 32; i += 8)
    tile[ty + i][tx] = src[(size_t)(r0 + ty + i) * C + c0 + tx];
  __syncthreads();
  #pragma unroll
  for (int i = 0; i < 32; i += 8)
    dst[(size_t)(c0 + ty + i) * R + r0 + tx] = (_Float16)tile[tx][ty + i];
}

// ---------------------------------------------------------------- cast
__global__ __launch_bounds__(256)
void cast_f32_f16(const float* __restrict__ src, _Float16* __restrict__ dst, int n4)
{
  int i = blockIdx.x * 256 + threadIdx.x;
  if (i >= n4) return;
  float4 v = ((const float4*)src)[i];
  v4h h = {(_Float16)v.x, (_Float16)v.y, (_Float16)v.z, (_Float16)v.w};
  *(v4h*)&dst[4 * (size_t)i] = h;
}

// ---------------------------------------------------------------- GEMM 256x256 8-phase
// C[M][N] = A[M][K] * Bt[N][K]^T, fp16 in, fp32 accumulate.
// MODE 0: fp32 store. 1: silu -> f16. 2: +bias -> f16. 3: plain f16.
// (structure unchanged from Round 5 -- see that round's derivation)
template<int MODE>
__global__ __launch_bounds__(512, 2)
void gemm256(const _Float16* __restrict__ A, const _Float16* __restrict__ Bt,
             void* __restrict__ Cout, const float* __restrict__ bias,
             int M, int N, int K)
{
  __shared__ _Float16 lds[65536];   // 128 KiB
  const int tid  = threadIdx.x;
  const int lane = tid & 63;
  const int wid  = tid >> 6;
  const int wm   = wid >> 2;        // 0..1
  const int wn   = wid & 3;         // 0..3
  const int l16  = lane & 15;
  const int q8   = (lane >> 4) * 8;
  const int swzx = (l16 & 7) << 3;  // row&7 == l16&7 for all frag rows

  // XCD-aware bijective swizzle (gridDim.x % 8 == 0 at all call sites)
  const int nbx = N >> 8;
  const int cpx = gridDim.x >> 3;
  const int swz = (blockIdx.x & 7) * cpx + (blockIdx.x >> 3);
  const int bm0 = (swz / nbx) << 8;
  const int bn0 = (swz % nbx) << 8;

  const _Float16* Abase = A  + (size_t)bm0 * K;
  const _Float16* Bbase = Bt + (size_t)bn0 * K;

  const int r0 = tid >> 3;                              // 0..63
  const int cs = ((tid & 7) * 8) ^ ((r0 & 7) << 3);     // f16 units

#define SLOTA(par, half) (lds + ((par) * 2 + (half)) * 8192)
#define SLOTB(par, half) (lds + 32768 + ((par) * 2 + (half)) * 8192)
#define STAGE(basep, kt, slot) do {                                        \
    _Float16* sst_ = (slot);                                               \
    gload16((basep) + (size_t)r0 * K + (kt) + cs, sst_ + tid * 8);         \
    gload16((basep) + (size_t)(r0 + 64) * K + (kt) + cs,                   \
            sst_ + 4096 + tid * 8);                                        \
  } while (0)
#define LOADA(par, mh) do {                                                \
    const _Float16* sld_ = SLOTA(par, mh);                                 \
    _Pragma("unroll")                                                      \
    for (int ks = 0; ks < 2; ks++)                                         \
      _Pragma("unroll")                                                    \
      for (int mi = 0; mi < 4; mi++)                                       \
        af[ks][mi] = *(const v8h*)&sld_[(wm * 64 + mi * 16 + l16) * 64 +   \
                                        ((ks * 32 + q8) ^ swzx)];          \
  } while (0)
#define LOADB(par, nh) do {                                                \
    const _Float16* sld_ = SLOTB(par, nh);                                 \
    _Pragma("unroll")                                                      \
    for (int ks = 0; ks < 2; ks++)                                         \
      _Pragma("unroll")                                                    \
      for (int ni = 0; ni < 2; ni++)                                       \
        bf[ks][ni] = *(const v8h*)&sld_[(wn * 32 + ni * 16 + l16) * 64 +   \
                                        ((ks * 32 + q8) ^ swzx)];          \
  } while (0)
#define MMAC(mh, nh) do {                                                  \
    __builtin_amdgcn_s_setprio(1);                                         \
    _Pragma("unroll")                                                      \
    for (int ks = 0; ks < 2; ks++)                                         \
      _Pragma("unroll")                                                    \
      for (int mi = 0; mi < 4; mi++)                                       \
        _Pragma("unroll")                                                  \
        for (int ni = 0; ni < 2; ni++)                                     \
          acc[mh][mi][nh][ni] = __builtin_amdgcn_mfma_f32_16x16x32_f16(    \
              af[ks][mi], bf[ks][ni], acc[mh][mi][nh][ni], 0, 0, 0);       \
    __builtin_amdgcn_s_setprio(0);                                         \
  } while (0)

  v4f acc[2][4][2][2];
  #pragma unroll
  for (int mh = 0; mh < 2; mh++)
    #pragma unroll
    for (int mi = 0; mi < 4; mi++)
      #pragma unroll
      for (int nh = 0; nh < 2; nh++)
        #pragma unroll
        for (int ni = 0; ni < 2; ni++)
          acc[mh][mi][nh][ni] = v4f{0.f, 0.f, 0.f, 0.f};
  v8h af[2][4], bf[2][2];

  const int nt = K >> 6;   // >= 32 at all call sites

  // prologue: tile0 fully + t1.Aa + t1.Bb (steady-state pattern primed)
  STAGE(Abase,                   0,  SLOTA(0, 0));
  STAGE(Bbase,                   0,  SLOTB(0, 0));
  STAGE(Abase + (size_t)128 * K, 0,  SLOTA(0, 1));
  STAGE(Bbase + (size_t)128 * K, 0,  SLOTB(0, 1));
  STAGE(Abase,                   64, SLOTA(1, 0));
  STAGE(Bbase + (size_t)128 * K, 64, SLOTB(1, 1));
  asm volatile("s_waitcnt vmcnt(4)" ::: "memory");
  __builtin_amdgcn_s_barrier();

  for (int T = 0; T < nt; T++) {
    const int par = T & 1;
    const int kt1 = (T + 1) << 6;
    const int kt2 = (T + 2) << 6;
    // ph1 (0,0)
    LOADA(par, 0);
    LOADB(par, 0);
    if (T + 1 < nt) STAGE(Abase + (size_t)128 * K, kt1, SLOTA(par ^ 1, 1));
    __builtin_amdgcn_s_barrier();
    MMAC(0, 0);
    __builtin_amdgcn_s_barrier();
    // ph2 (0,1)
    LOADB(par, 1);
    if (T + 1 < nt) STAGE(Bbase, kt1, SLOTB(par ^ 1, 0));
    __builtin_amdgcn_s_barrier();
    MMAC(0, 1);
    __builtin_amdgcn_s_barrier();
    // ph3 (1,1)
    LOADA(par, 1);
    if (T + 2 < nt) STAGE(Abase, kt2, SLOTA(par, 0));
    __builtin_amdgcn_s_barrier();
    MMAC(1, 1);
    __builtin_amdgcn_s_barrier();
    // ph4 (1,0)
    LOADB(par, 0);
    if (T + 2 < nt) STAGE(Bbase + (size_t)128 * K, kt2, SLOTB(par, 1));
    __builtin_amdgcn_s_barrier();
    MMAC(1, 0);
    if (T + 2 < nt) { asm volatile("s_waitcnt vmcnt(4)" ::: "memory"); }
    else            { asm volatile("s_waitcnt vmcnt(0)" ::: "memory"); }
    __builtin_amdgcn_s_barrier();
  }

  const int q4 = (lane >> 4) * 4;
  #pragma unroll
  for (int mh = 0; mh < 2; mh++) {
    #pragma unroll
    for (int mi = 0; mi < 4; mi++) {
      #pragma unroll
      for (int nh = 0; nh < 2; nh++) {
        #pragma unroll
        for (int ni = 0; ni < 2; ni++) {
          const int gn = bn0 + nh * 128 + wn * 32 + ni * 16 + l16;
          #pragma unroll
          for (int r = 0; r < 4; r++) {
            const int gm = bm0 + mh * 128 + wm * 64 + mi * 16 + q4 + r;
            float val = acc[mh][mi][nh][ni][r];
            size_t offc = (size_t)gm * N + gn;
            if (MODE == 0) {
              ((float*)Cout)[offc] = val;
            } else if (MODE == 1) {
              float s = val / (1.0f + expf(-val));
              ((_Float16*)Cout)[offc] = (_Float16)s;
            } else if (MODE == 2) {
              float s = val + bias[gn];
              ((_Float16*)Cout)[offc] = (_Float16)s;
            } else {
              ((_Float16*)Cout)[offc] = (_Float16)val;
            }
          }
        }
      }
    }
  }
#undef SLOTA
#undef SLOTB
#undef STAGE
#undef LOADA
#undef LOADB
#undef MMAC
}

// ---------------------------------------------------------------- conv + silu (per 2048-row chunk == one batch)
__global__ __launch_bounds__(256)
void conv_silu(const _Float16* __restrict__ vg, const _Float16* __restrict__ kernc,
               float* __restrict__ vprime, int chunk)
{
  int idx = blockIdx.x * 256 + threadIdx.x;   // 2048*2048
  int btl = idx >> 11;                        // 0..2047 == t (chunk aligned to batch)
  int d   = idx & 2047;
  int btg = chunk * 2048 + btl;
  v4h kv = *(const v4h*)&kernc[(size_t)btl * 8192 + d * 4];
  float kw0 = (float)kv[0], kw1 = (float)kv[1], kw2 = (float)kv[2], kw3 = (float)kv[3];
  const _Float16* vcol = vg + d;
  float acc = kw3 * (float)vcol[(size_t)btg * 4096];
  if (btl >= 1) acc += kw2 * (float)vcol[(size_t)(btg - 1) * 4096];
  if (btl >= 2) acc += kw1 * (float)vcol[(size_t)(btg - 2) * 4096];
  if (btl >= 3) acc += kw0 * (float)vcol[(size_t)(btg - 3) * 4096];
  vprime[(size_t)btg * 2048 + d] = acc / (1.0f + expf(-acc));
}

// ---------------------------------------------------------------- beta / glog (fp32 x)
__global__ __launch_bounds__(256)
void beta_decay(const float* __restrict__ x, const float* __restrict__ Wb,
                const float* __restrict__ Wa, const float* __restrict__ dt_bias,
                const float* __restrict__ A_log,
                float* __restrict__ beta, float* __restrict__ glog)
{
  __shared__ float xs[2048];
  __shared__ float red[8][32];
  int row = blockIdx.x;
  int tid = threadIdx.x;
  for (int i = tid; i < 2048; i += 256) xs[i] = x[(size_t)row * 2048 + i];
  __syncthreads();
  int j = tid & 31, kg = tid >> 5;
  const float* W = (j < 16) ? Wb : Wa;
  int jj = j & 15;
  float acc = 0.f;
  int k0 = kg * 256;
  for (int k = k0; k < k0 + 256; k++) acc += xs[k] * W[(size_t)k * 16 + jj];
  red[kg][j] = acc;
  __syncthreads();
  if (tid < 32) {
    float s = 0.f;
    #pragma unroll
    for (int g2 = 0; g2 < 8; g2++) s += red[g2][tid];
    int hh = tid & 15;
    if (tid < 16) {
      beta[(size_t)row * 16 + hh] = 1.0f / (1.0f + expf(-s));
    } else {
      float tt = s + dt_bias[hh];
      float sp = (tt > 20.f) ? tt : log1pf(expf(tt));
      glog[(size_t)row * 16 + hh] = -expf(A_log[hh]) * sp;
    }
  }
}

// ---------------------------------------------------------------- segmented chunked recurrence (Round 8)
// 192 blocks: role = blockIdx.x>>6. role 0: seg0 real (write o[0:1024] +
// S_end fp32). role 1: seg1 real, S0=0 (write o_local[1024:2048]).
// role 2: seg1 basis, S0=I, V=0 (write o_basis fp16 = q_hat^T Phi_before).
// Within-role geometry identical to Round 7 (64 blocks = b x h x dv-half,
// chunk C=32, UT transform; 32 chunks per segment).
// KT16 stores are XOR-swizzled: element (row,col) at col ^ (((row>>4)&3)<<3)
// -- breaks the 16k*80 = 0 mod 128 bank degeneracy (16-way -> 4-way).
__global__ __launch_bounds__(256)
void recurrence_seg(const _Float16* __restrict__ gi,
                    const float* __restrict__ vprime,
                    const float* __restrict__ betab,
                    const float* __restrict__ glogb,
                    float* __restrict__ o,
                    float* __restrict__ Send,
                    _Float16* __restrict__ obasis)
{
  __shared__ _Float16 Q16[32][136];
  __shared__ _Float16 K16[32][136];
  __shared__ _Float16 KT16[2][128][40];   // K^T, double-buffered, col-swizzled
  __shared__ _Float16 St16[64][136];      // fp16 shadow of state (dv-major)
  __shared__ float V32[32][68];
  __shared__ float W0L[32][65];           // K*S0
  __shared__ float O0L[32][65];           // Q*S0
  __shared__ float At32[32][32];          // A transposed [j][i], upper zeroed
  __shared__ _Float16 B16[32][40];        // B matrix fp16 (row-major)
  __shared__ _Float16 Ut16[64][40];       // U^T fp16 (dv-major)
  __shared__ _Float16 Utp16[64][40];      // U^T scaled by P31/P_j
  __shared__ float lgA[2][32], lgm1A[2][32], gm1E[2][32], bGA[2][32],
                   psA[2][32], betA[2][32], p31A[2];

  const int tid  = threadIdx.x;
  const int wid  = tid >> 6;
  const int lane = tid & 63;
  const int l16  = lane & 15;
  const int q8   = (lane >> 4) * 8;
  const int q4   = (lane >> 4) * 4;
  const int rg   = lane >> 4;            // solve: row group (8 rows)
  const int wc   = wid * 16 + l16;       // solve: dv column (0..63)

  const int role = blockIdx.x >> 6;      // 0,1,2
  const int blk  = blockIdx.x & 63;
  const int dvh  = blk & 1;
  const int h    = (blk >> 1) & 15;
  const int b    = blk >> 5;
  const int tbase = (role == 0) ? 0 : 1024;
  const bool basis = (role == 2);

  const _Float16* gq = gi + (size_t)b * 2048 * 4096 + h * 128;
  const _Float16* gk = gq + 2048;
  const float* vsrc = vprime + (size_t)b * 2048 * 2048 + h * 128 + dvh * 64;
  float* ob = o + ((size_t)(b * 2048 + tbase) * 16 + h) * 128 + dvh * 64;
  _Float16* obb = obasis + ((size_t)b * 1024 * 16 + h) * 128 + dvh * 64;

  const int sr  = tid >> 3;              // staging row 0..31
  const int sc8 = tid & 7;
  const int c0  = sc8 * 16;              // q/k col base (16 f16 per thread)
  const int ktsw = (tid & 3) << 3;       // KT16 write swizzle = ((row>>4)&3)<<3

  v4f sfr[8];                            // state frags [dv x dk] tiles
  #pragma unroll
  for (int tn = 0; tn < 8; tn++) {
    #pragma unroll
    for (int fr = 0; fr < 4; fr++)
      sfr[tn][fr] = (basis && (tn * 16 + l16) == (dvh * 64 + wid * 16 + q4 + fr))
                        ? 1.f : 0.f;
  }

  v8h pq0, pq1, pk0, pk1;
  float4 pv0 = {0.f, 0.f, 0.f, 0.f}, pv1 = {0.f, 0.f, 0.f, 0.f};
  float pg = 0.f, pb = 0.f;

  auto stage_regs = [&](int t0) {
    pq0 = *(const v8h*)(gq + (size_t)(t0 + sr) * 4096 + c0);
    pq1 = *(const v8h*)(gq + (size_t)(t0 + sr) * 4096 + c0 + 8);
    pk0 = *(const v8h*)(gk + (size_t)(t0 + sr) * 4096 + c0);
    pk1 = *(const v8h*)(gk + (size_t)(t0 + sr) * 4096 + c0 + 8);
    if (!basis) {
      pv0 = *(const float4*)(vsrc + (size_t)(t0 + sr) * 2048 + sc8 * 8);
      pv1 = *(const float4*)(vsrc + (size_t)(t0 + sr) * 2048 + sc8 * 8 + 4);
    }
    if (tid < 32) {
      size_t bt_ = (size_t)(b * 2048 + t0 + tid) * 16 + h;
      pg = glogb[bt_];
      pb = betab[bt_];
    }
  };

  auto write_stage = [&](int pn) {
    float qf[16], kf[16];
    #pragma unroll
    for (int m = 0; m < 8; m++) {
      qf[m] = (float)pq0[m]; qf[m + 8] = (float)pq1[m];
      kf[m] = (float)pk0[m]; kf[m + 8] = (float)pk1[m];
    }
    float ssq = 0.f, ssk = 0.f;
    #pragma unroll
    for (int m = 0; m < 16; m++) { ssq += qf[m] * qf[m]; ssk += kf[m] * kf[m]; }
    ssq += __shfl_xor(ssq, 1); ssq += __shfl_xor(ssq, 2); ssq += __shfl_xor(ssq, 4);
    ssk += __shfl_xor(ssk, 1); ssk += __shfl_xor(ssk, 2); ssk += __shfl_xor(ssk, 4);
    float iq = 1.0f / fmaxf(sqrtf(ssq), 1e-12f);
    float ik = 1.0f / fmaxf(sqrtf(ssk), 1e-12f);
    v8h qo0, qo1, ko0, ko1;
    #pragma unroll
    for (int m = 0; m < 8; m++) {
      qo0[m] = (_Float16)(qf[m] * iq); qo1[m] = (_Float16)(qf[m + 8] * iq);
      ko0[m] = (_Float16)(kf[m] * ik); ko1[m] = (_Float16)(kf[m + 8] * ik);
    }
    *(v8h*)&Q16[sr][c0]     = qo0;
    *(v8h*)&Q16[sr][c0 + 8] = qo1;
    *(v8h*)&K16[sr][c0]     = ko0;
    *(v8h*)&K16[sr][c0 + 8] = ko1;
    #pragma unroll
    for (int m = 0; m < 8; m++) {
      KT16[pn][c0 + m][sr ^ ktsw]     = ko0[m];
      KT16[pn][c0 + 8 + m][sr ^ ktsw] = ko1[m];
    }
    *(float4*)&V32[sr][sc8 * 8]     = pv0;
    *(float4*)&V32[sr][sc8 * 8 + 4] = pv1;
    if (tid < 32) {
      float s = pg;
      #pragma unroll
      for (int d = 1; d < 32; d <<= 1) {
        float t = __shfl_up(s, d, 64);
        if (lane >= d) s += t;
      }
      float lg31 = __shfl(s, 31, 64);
      float lgm1 = s - pg;               // log prod_{m<i} g_m
      lgA[pn][lane]   = s;
      lgm1A[pn][lane] = lgm1;
      float g1 = expf(lgm1);
      gm1E[pn][lane]  = g1;
      bGA[pn][lane]   = pb * g1;
      psA[pn][lane]   = expf(lg31 - s);  // P31/P_j <= 1
      betA[pn][lane]  = pb;
      if (lane == 0) p31A[pn] = expf(lg31);
    }
  };

  // ---- preloop: stage chunk 0, init state shadow (0 or I) ----
  stage_regs(tbase);
  for (int i = tid; i < 64 * 136; i += 256) {
    int r_ = i / 136, cc_ = i - r_ * 136;
    (&St16[0][0])[i] =
        (basis && cc_ == dvh * 64 + r_) ? (_Float16)1.f : (_Float16)0.f;
  }
  write_stage(0);
  __syncthreads();

  const v4f zf = {0.f, 0.f, 0.f, 0.f};

  for (int c = 0; c < 32; c++) {
    const int par = c & 1;

    // ================= phase A: dense MFMAs + A/B assembly =================
    if (c < 31) { stage_regs(tbase + (c + 1) * 32); __builtin_amdgcn_sched_barrier(0); }

    v4f kkf = zf, qkf = zf, w0f0 = zf, w0f1 = zf, o0f0 = zf, o0f1 = zf;
    {
      const int ai = (wid >> 1) * 16 + l16;  // KK/QK A rows (i)
      const int bj = (wid & 1) * 16 + l16;   // KK/QK B rows (j)
      #pragma unroll
      for (int ks = 0; ks < 4; ks++) {
        const int ko = ks * 32 + q8;
        v8h bs  = *(const v8h*)&St16[wid * 16 + l16][ko];  // S0 dv-slice
        v8h ak0 = *(const v8h*)&K16[l16][ko];
        v8h ak1 = *(const v8h*)&K16[16 + l16][ko];
        v8h aq0 = *(const v8h*)&Q16[l16][ko];
        v8h aq1 = *(const v8h*)&Q16[16 + l16][ko];
        w0f0 = __builtin_amdgcn_mfma_f32_16x16x32_f16(ak0, bs, w0f0, 0, 0, 0);
        w0f1 = __builtin_amdgcn_mfma_f32_16x16x32_f16(ak1, bs, w0f1, 0, 0, 0);
        o0f0 = __builtin_amdgcn_mfma_f32_16x16x32_f16(aq0, bs, o0f0, 0, 0, 0);
        o0f1 = __builtin_amdgcn_mfma_f32_16x16x32_f16(aq1, bs, o0f1, 0, 0, 0);
        v8h akk = *(const v8h*)&K16[ai][ko];
        v8h aqq = *(const v8h*)&Q16[ai][ko];
        v8h bkk = *(const v8h*)&K16[bj][ko];
        kkf = __builtin_amdgcn_mfma_f32_16x16x32_f16(akk, bkk, kkf, 0, 0, 0);
        qkf = __builtin_amdgcn_mfma_f32_16x16x32_f16(aqq, bkk, qkf, 0, 0, 0);
      }
    }
    {
      const int i0 = (wid >> 1) * 16, j = (wid & 1) * 16 + l16;
      #pragma unroll
      for (int fr = 0; fr < 4; fr++) {
        const int i = i0 + q4 + fr;
        float ex = expf(fminf(lgm1A[par][i] - lgA[par][j], 0.f));
        const bool lt = (j < i);
        At32[j][i] = lt ? betA[par][i] * ex * kkf[fr] : 0.f;
        B16[i][j]  = lt ? (_Float16)(ex * qkf[fr]) : (_Float16)0.f;
      }
      #pragma unroll
      for (int fr = 0; fr < 4; fr++) {
        W0L[q4 + fr][wid * 16 + l16]      = w0f0[fr];
        W0L[16 + q4 + fr][wid * 16 + l16] = w0f1[fr];
        O0L[q4 + fr][wid * 16 + l16]      = o0f0[fr];
        O0L[16 + q4 + fr][wid * 16 + l16] = o0f1[fr];
      }
    }
    __syncthreads();

    // ================= phase B: triangular solve (I+A)U = R =================
    float ru[8];
    #pragma unroll
    for (int jj = 0; jj < 8; jj++) {
      const int row = rg * 8 + jj;
      ru[jj] = betA[par][row] * V32[row][wc] - bGA[par][row] * W0L[row][wc];
    }
    #pragma unroll
    for (int j = 0; j < 32; j++) {
      float uj = __shfl(ru[j & 7], (j >> 3) * 16 + l16, 64);
      const v4f a0 = *(const v4f*)&At32[j][rg * 8];
      const v4f a1 = *(const v4f*)&At32[j][rg * 8 + 4];
      ru[0] -= a0[0] * uj; ru[1] -= a0[1] * uj;
      ru[2] -= a0[2] * uj; ru[3] -= a0[3] * uj;
      ru[4] -= a1[0] * uj; ru[5] -= a1[1] * uj;
      ru[6] -= a1[2] * uj; ru[7] -= a1[3] * uj;
    }
    {
      v8h uo, upo;
      #pragma unroll
      for (int jj = 0; jj < 8; jj++) {
        uo[jj]  = (_Float16)ru[jj];
        upo[jj] = (_Float16)(ru[jj] * psA[par][rg * 8 + jj]);
      }
      *(v8h*)&Ut16[wc][rg * 8]  = uo;
      *(v8h*)&Utp16[wc][rg * 8] = upo;
    }
    __syncthreads();

    // ================= phase C: O = Gm1*O0 + B U ; S = P31*S + Kp^T U =======
    {
      v8h bu = *(const v8h*)&Ut16[wid * 16 + l16][q8];
      #pragma unroll
      for (int t2i = 0; t2i < 2; t2i++) {
        v8h a = *(const v8h*)&B16[t2i * 16 + l16][q8];
        v4f d = __builtin_amdgcn_mfma_f32_16x16x32_f16(a, bu, zf, 0, 0, 0);
        #pragma unroll
        for (int fr = 0; fr < 4; fr++) {
          const int i = t2i * 16 + q4 + fr;
          const int cc = wid * 16 + l16;
          float val = gm1E[par][i] * O0L[i][cc] + d[fr];
          size_t off = (size_t)(c * 32 + i) * 2048 + cc;
          if (basis) obb[off] = (_Float16)val;
          else       ob[off] = val;
        }
      }
      const float p31 = p31A[par];
      v8h ua = *(const v8h*)&Utp16[wid * 16 + l16][q8];
      #pragma unroll
      for (int tn = 0; tn < 8; tn++) {
        v8h bk = *(const v8h*)&KT16[par][tn * 16 + l16][q8 ^ ((tn & 3) << 3)];
        v4f sc = {sfr[tn][0] * p31, sfr[tn][1] * p31,
                  sfr[tn][2] * p31, sfr[tn][3] * p31};
        sfr[tn] = __builtin_amdgcn_mfma_f32_16x16x32_f16(ua, bk, sc, 0, 0, 0);
        #pragma unroll
        for (int fr = 0; fr < 4; fr++)
          St16[wid * 16 + q4 + fr][tn * 16 + l16] = (_Float16)sfr[tn][fr];
      }
    }
    if (c < 31) write_stage((c + 1) & 1);
    __syncthreads();
  }

  // seg0-real: export final state fp32 (= S_in for seg1)
  if (role == 0) {
    float* sg = Send + (size_t)(b * 16 + h) * 128 * 128;
    #pragma unroll
    for (int tn = 0; tn < 8; tn++)
      #pragma unroll
      for (int fr = 0; fr < 4; fr++)
        sg[(size_t)(dvh * 64 + wid * 16 + q4 + fr) * 128 + tn * 16 + l16] =
            sfr[tn][fr];
  }
}

// ---------------------------------------------------------------- apply basis correction
// o[b, 1024+t, h, :] += o_basis[b, t, h, :dk] @ S_end[b,h][dv][dk]^T
// 256 blocks = 32 (b,h) x 8 t-tiles of 128. 4 waves; per wave 32 rows.
__global__ __launch_bounds__(256)
void apply_basis(const _Float16* __restrict__ obasis,
                 const float* __restrict__ Send,
                 float* __restrict__ o)
{
  __shared__ _Float16 Ao[128][136];
  __shared__ _Float16 Bs[128][136];
  const int bh = blockIdx.x & 31;
  const int tt = blockIdx.x >> 5;       // 0..7
  const int b = bh >> 4, h = bh & 15;
  const int tid = threadIdx.x;
  const int wid = tid >> 6, lane = tid & 63;
  const int l16 = lane & 15, q8 = (lane >> 4) * 8, q4 = (lane >> 4) * 4;

  const _Float16* asrc = obasis + ((size_t)(b * 1024 + tt * 128) * 16 + h) * 128;
  for (int i = tid; i < 128 * 16; i += 256) {
    int r = i >> 4, c8 = (i & 15) * 8;
    *(v8h*)&Ao[r][c8] = *(const v8h*)(asrc + (size_t)r * 2048 + c8);
  }
  const float* ssrc = Send + (size_t)bh * 128 * 128;
  for (int i = tid; i < 128 * 16; i += 256) {
    int r = i >> 4, c8 = (i & 15) * 8;
    v8h tmp;
    #pragma unroll
    for (int m = 0; m < 8; m++) tmp[m] = (_Float16)ssrc[(size_t)r * 128 + c8 + m];
    *(v8h*)&Bs[r][c8] = tmp;            // Bs[dv][dk]
  }
  __syncthreads();

  v4f acc[2][8];
  #pragma unroll
  for (int rt = 0; rt < 2; rt++)
    #pragma unroll
    for (int ct = 0; ct < 8; ct++) acc[rt][ct] = v4f{0.f, 0.f, 0.f, 0.f};
  #pragma unroll
  for (int ks = 0; ks < 4; ks++) {
    v8h af0 = *(const v8h*)&Ao[wid * 32 + l16][ks * 32 + q8];
    v8h af1 = *(const v8h*)&Ao[wid * 32 + 16 + l16][ks * 32 + q8];
    #pragma unroll
    for (int ct = 0; ct < 8; ct++) {
      v8h bf = *(const v8h*)&Bs[ct * 16 + l16][ks * 32 + q8];
      acc[0][ct] = __builtin_amdgcn_mfma_f32_16x16x32_f16(af0, bf, acc[0][ct], 0, 0, 0);
      acc[1][ct] = __builtin_amdgcn_mfma_f32_16x16x32_f16(af1, bf, acc[1][ct], 0, 0, 0);
    }
  }
  float* obp = o + ((size_t)(b * 2048 + 1024 + tt * 128) * 16 + h) * 128;
  #pragma unroll
  for (int rt = 0; rt < 2; rt++) {
    #pragma unroll
    for (int ct = 0; ct < 8; ct++) {
      #pragma unroll
      for (int fr = 0; fr < 4; fr++) {
        const int row = wid * 32 + rt * 16 + q4 + fr;
        const int col = ct * 16 + l16;
        obp[(size_t)row * 2048 + col] += acc[rt][ct][fr];
      }
    }
  }
}

// ---------------------------------------------------------------- rmsnorm * silu(gate)
__global__ __launch_bounds__(256)
void rms_gate(const float* __restrict__ o, const _Float16* __restrict__ vg,
              const float* __restrict__ normw, _Float16* __restrict__ yh)
{
  int task = blockIdx.x * 4 + (threadIdx.x >> 6);  // bt*16+h, 0..65535
  int lane = threadIdx.x & 63;
  int bt = task >> 4, h = task & 15;
  float2 v = *(const float2*)(o + (size_t)task * 128 + lane * 2);
  float ss = v.x * v.x + v.y * v.y;
  #pragma unroll
  for (int m = 1; m < 64; m <<= 1) ss += __shfl_xor(ss, m);
  float r = rsqrtf(ss * (1.0f / 128.0f) + 1e-6f);
  v2h gt2 = *(const v2h*)(vg + (size_t)bt * 4096 + 2048 + h * 128 + lane * 2);
  float gx = (float)gt2[0], gy = (float)gt2[1];
  float2 nw = *(const float2*)(normw + lane * 2);
  float g0 = gx / (1.0f + expf(-gx));
  float g1 = gy / (1.0f + expf(-gy));
  v2h outp = {(_Float16)(v.x * r * nw.x * g0), (_Float16)(v.y * r * nw.y * g1)};
  *(v2h*)(yh + (size_t)bt * 2048 + h * 128 + lane * 2) = outp;
}

// ---------------------------------------------------------------- launch
extern "C" void kernel_launch(void* const* d_in, const int* in_sizes, int n_in,
                              void* d_out, int out_size, void* d_ws, size_t ws_size,
                              hipStream_t stream)
{
  (void)in_sizes; (void)n_in; (void)out_size;
  const float* x       = (const float*)d_in[0];
  const float* Wq      = (const float*)d_in[1];
  const float* Wk      = (const float*)d_in[2];
  const float* Wv      = (const float*)d_in[3];
  const float* Wb      = (const float*)d_in[4];
  const float* Wa      = (const float*)d_in[5];
  const float* dt_bias = (const float*)d_in[6];
  const float* A_log   = (const float*)d_in[7];
  const float* gen_w1  = (const float*)d_in[8];
  const float* gen_w2  = (const float*)d_in[9];
  const float* gen_b2  = (const float*)d_in[10];
  const float* normw   = (const float*)d_in[11];
  const float* Wg      = (const float*)d_in[12];
  const float* Wo      = (const float*)d_in[13];

  // ---- workspace pool (explicit aliasing; peak ~185 MB, known to fit) ----
  const size_t SZ_GI   = 4096ull * 4096 * 2;   // 33.5 MB  f16 q|k (pre-norm)
  const size_t SZ_VG   = 4096ull * 4096 * 2;   // 33.5 MB  f16 v|gate
  const size_t SZ_WT   = 8192ull * 2048 * 2;   // 33.5 MB  f16 transposed weights (reused)
  const size_t SZ_D    = 4096ull * 2048 * 2;   // 16.8 MB  xh -> hid -> yh
  const size_t SZ_KC   = 2048ull * 8192 * 2;   // 33.5 MB  kern chunk (reused)
  const size_t SZ_VP   = 4096ull * 2048 * 4;   // 33.5 MB  fp32 v'
  const size_t SZ_SM   = 4096ull * 16 * 4;     //  0.26 MB x2
  const size_t NEEDED = SZ_GI + SZ_VG + SZ_WT + SZ_D + SZ_KC + SZ_VP + 2 * SZ_SM;
  if (ws_size < NEEDED) return;

  char* w = (char*)d_ws;
  _Float16* gi     = (_Float16*)(w);
  _Float16* vg     = (_Float16*)(w + SZ_GI);
  _Float16* Wt     = (_Float16*)(w + SZ_GI + SZ_VG);
  char*     Dreg   =            (w + SZ_GI + SZ_VG + SZ_WT);
  _Float16* kernc  = (_Float16*)(w + SZ_GI + SZ_VG + SZ_WT + SZ_D);
  float*    vprime = (float*)   (w + SZ_GI + SZ_VG + SZ_WT + SZ_D + SZ_KC);
  float*    betab  = (float*)   (w + SZ_GI + SZ_VG + SZ_WT + SZ_D + SZ_KC + SZ_VP);
  float*    glogb  = (float*)   (w + SZ_GI + SZ_VG + SZ_WT + SZ_D + SZ_KC + SZ_VP + SZ_SM);
  _Float16* xh  = (_Float16*)Dreg;  // until G1b
  _Float16* hid = (_Float16*)Dreg;  // G2 -> G3
  _Float16* yh  = (_Float16*)Dreg;  // rms_gate -> G4
  float* obuf = (float*)d_out;      // o lives in d_out until G4 overwrites

  // recurrence scratch aliases Wt (dead between G3 gemms and G4 transpose):
  // obasis 8.39 MB f16, Send 2.1 MB fp32
  _Float16* obasis = (_Float16*)(w + SZ_GI + SZ_VG);
  float*    Send   = (float*)   (w + SZ_GI + SZ_VG + 2ull * 1024 * 16 * 128 * 2);

  dim3 blk(256);
  dim3 blk512(512);

  cast_f32_f16<<<8192, blk, 0, stream>>>(x, xh, 4096 * 2048 / 4);

  // G1a: q|k  (M=4096, N=4096, K=2048 -> 256 wgs)
  transpose_cast<<<dim3(64, 64), blk, 0, stream>>>(Wq, Wt, 2048, 2048);
  transpose_cast<<<dim3(64, 64), blk, 0, stream>>>(Wk, Wt + 2048 * 2048, 2048, 2048);
  gemm256<3><<<256, blk512, 0, stream>>>(xh, Wt, gi, nullptr, 4096, 4096, 2048);

  // G1b: v|gate
  transpose_cast<<<dim3(64, 64), blk, 0, stream>>>(Wv, Wt, 2048, 2048);
  transpose_cast<<<dim3(64, 64), blk, 0, stream>>>(Wg, Wt + 2048 * 2048, 2048, 2048);
  gemm256<3><<<256, blk512, 0, stream>>>(xh, Wt, vg, nullptr, 4096, 4096, 2048);

  // G2: hid = silu(gi @ gen_w1)  (M=4096, N=2048, K=4096 -> 128 wgs)
  transpose_cast<<<dim3(64, 128), blk, 0, stream>>>(gen_w1, Wt, 4096, 2048);
  gemm256<1><<<128, blk512, 0, stream>>>(gi, Wt, hid, nullptr, 4096, 2048, 4096);

  // G3 + conv, chunked per batch  (M=2048, N=8192, K=2048 -> 256 wgs)
  transpose_cast<<<dim3(256, 64), blk, 0, stream>>>(gen_w2, Wt, 2048, 8192);
  for (int chunk = 0; chunk < 2; chunk++) {
    gemm256<2><<<256, blk512, 0, stream>>>(hid + (size_t)chunk * 2048 * 2048, Wt,
                                           kernc, gen_b2, 2048, 8192, 2048);
    conv_silu<<<16384, blk, 0, stream>>>(vg, kernc, vprime, chunk);
  }

  beta_decay<<<4096, blk, 0, stream>>>(x, Wb, Wa, dt_bias, A_log, betab, glogb);
  recurrence_seg<<<192, blk, 0, stream>>>(gi, vprime, betab, glogb, obuf,
                                          Send, obasis);
  apply_basis<<<256, blk, 0, stream>>>(obasis, Send, obuf);
  rms_gate<<<16384, blk, 0, stream>>>(obuf, vg, normw, yh);

  // G4: out = y @ Wo  (M=4096, N=2048, K=2048 -> 128 wgs)
  transpose_cast<<<dim3(64, 64), blk, 0, stream>>>(Wo, Wt, 2048, 2048);
  gemm256<0><<<128, blk512, 0, stream>>>(yh, Wt, (float*)d_out, nullptr, 4096, 2048, 2048);
}